// Round 1
// baseline (871.456 us; speedup 1.0000x reference)
//
#include <hip/hip_runtime.h>

#define N_NODES 50000
#define E_EDGES 800000
#define IN_F    128
#define H_F     64
#define STD_EPS 1e-5f
#define BN_EPS  1e-5f

// ---------------------------------------------------------------- degree hist
__global__ __launch_bounds__(256) void k_hist(const int* __restrict__ dst,
                                              int* __restrict__ deg) {
  int e = blockIdx.x * 256 + threadIdx.x;
  if (e < E_EDGES) atomicAdd(&deg[dst[e]], 1);
}

// ------------------------------------------------------- sum of log(deg+1)
__global__ __launch_bounds__(256) void k_sumlog(const int* __restrict__ deg,
                                                float* __restrict__ scalars) {
  __shared__ float red[256];
  int i = blockIdx.x * 256 + threadIdx.x;
  float v = 0.f;
  if (i < N_NODES) v = logf((float)deg[i] + 1.0f);
  red[threadIdx.x] = v; __syncthreads();
  for (int s = 128; s > 0; s >>= 1) {
    if (threadIdx.x < s) red[threadIdx.x] += red[threadIdx.x + s];
    __syncthreads();
  }
  if (threadIdx.x == 0) atomicAdd(&scalars[0], red[0]);
}

// ------------------------------------------------------------- scan (3-phase)
__global__ __launch_bounds__(256) void k_scan_part(const int* __restrict__ deg,
                                                   int* __restrict__ partials) {
  __shared__ int red[256];
  int base = blockIdx.x * 1024;
  int s = 0;
  for (int j = threadIdx.x; j < 1024; j += 256) {
    int i = base + j;
    if (i < N_NODES) s += deg[i];
  }
  red[threadIdx.x] = s; __syncthreads();
  for (int st = 128; st > 0; st >>= 1) {
    if (threadIdx.x < st) red[threadIdx.x] += red[threadIdx.x + st];
    __syncthreads();
  }
  if (threadIdx.x == 0) partials[blockIdx.x] = red[0];
}

__global__ void k_scan_mid(int* __restrict__ partials, int nblk,
                           float* __restrict__ scalars) {
  if (threadIdx.x == 0) {
    int run = 0;
    for (int b = 0; b < nblk; b++) { int v = partials[b]; partials[b] = run; run += v; }
    scalars[1] = scalars[0] / (float)N_NODES;   // avg_log
  }
}

__global__ __launch_bounds__(256) void k_scan_final(const int* __restrict__ deg,
                                                    const int* __restrict__ partials,
                                                    int* __restrict__ row_ptr,
                                                    int* __restrict__ cursor) {
  __shared__ int ts[256];
  int base = blockIdx.x * 1024 + threadIdx.x * 4;
  int d[4]; int s = 0;
#pragma unroll
  for (int j = 0; j < 4; j++) {
    int i = base + j;
    d[j] = (i < N_NODES) ? deg[i] : 0;
    s += d[j];
  }
  ts[threadIdx.x] = s; __syncthreads();
  for (int off = 1; off < 256; off <<= 1) {
    int t = (threadIdx.x >= off) ? ts[threadIdx.x - off] : 0;
    __syncthreads();
    ts[threadIdx.x] += t;
    __syncthreads();
  }
  int excl = (threadIdx.x > 0) ? ts[threadIdx.x - 1] : 0;
  int run = partials[blockIdx.x] + excl;
#pragma unroll
  for (int j = 0; j < 4; j++) {
    int i = base + j;
    if (i < N_NODES) { row_ptr[i] = run; cursor[i] = run; run += d[j]; }
  }
  if (blockIdx.x == 0 && threadIdx.x == 0) row_ptr[N_NODES] = E_EDGES;
}

// ------------------------------------------------------------------- scatter
__global__ __launch_bounds__(256) void k_scatter(const int* __restrict__ src,
                                                 const int* __restrict__ dst,
                                                 int* __restrict__ cursor,
                                                 int* __restrict__ csr_src) {
  int e = blockIdx.x * 256 + threadIdx.x;
  if (e < E_EDGES) {
    int d = dst[e];
    int p = atomicAdd(&cursor[d], 1);
    csr_src[p] = src[e];
  }
}

// --------------------------------------------------------------------- embed
// h = x @ embed_W + b   (50000,128)@(128,64)
// 16 nodes/group; thread = (col j, node-quad ng); x staged transposed in LDS.
__global__ __launch_bounds__(256) void k_embed(const float* __restrict__ x,
                                               const float* __restrict__ W,
                                               const float* __restrict__ bias,
                                               float* __restrict__ h) {
  __shared__ float sW[IN_F * 64];    // 32 KB
  __shared__ float sx[IN_F * 20];    // x_T[k][16+pad4]
  for (int i = threadIdx.x; i < IN_F * 64; i += 256) sW[i] = W[i];
  int j = threadIdx.x & 63, ng = threadIdx.x >> 6;
  float bj = bias[j];
  for (int grp = blockIdx.x; grp < N_NODES / 16; grp += gridDim.x) {
    int n0 = grp * 16;
    __syncthreads();
    for (int idx = threadIdx.x; idx < 16 * IN_F; idx += 256) {
      int nl = idx >> 7, k = idx & 127;
      sx[k * 20 + nl] = x[(size_t)(n0 + nl) * IN_F + k];
    }
    __syncthreads();
    float a0 = bj, a1 = bj, a2 = bj, a3 = bj;
    const float* xp = &sx[ng * 4];
#pragma unroll 4
    for (int k = 0; k < IN_F; k++) {
      float4 xv = *(const float4*)&xp[k * 20];
      float w = sW[k * 64 + j];
      a0 = fmaf(xv.x, w, a0); a1 = fmaf(xv.y, w, a1);
      a2 = fmaf(xv.z, w, a2); a3 = fmaf(xv.w, w, a3);
    }
    size_t ob = (size_t)(n0 + ng * 4) * 64 + j;
    h[ob] = a0; h[ob + 64] = a1; h[ob + 128] = a2; h[ob + 192] = a3;
  }
}

// ------------------------------------------------------------------ pre A/B
// hA[n, t*64+f] = preb[t,f] + sum_k h[n,k]*preW[t,k,f]       (bias folded)
// hB[n, t*64+f] =             sum_k h[n,k]*preW[t,64+k,f]
// BN variant: h_in = relu(y*scale+shift) applied at staging, h2 written out.
template <bool BN>
__global__ __launch_bounds__(256) void k_preab(const float* __restrict__ hin,
                                               const float* __restrict__ preW,
                                               const float* __restrict__ preb,
                                               const float* __restrict__ bnscale,
                                               const float* __restrict__ bnshift,
                                               float* __restrict__ h2out,
                                               float* __restrict__ hA,
                                               float* __restrict__ hB) {
  __shared__ float sW[2 * 128 * 64];   // 64 KB
  __shared__ float sh[64 * 12];        // h_T[k][8+pad4]
  for (int i = threadIdx.x; i < 2 * 128 * 64; i += 256) sW[i] = preW[i];
  int tf = threadIdx.x & 127, ng = threadIdx.x >> 7;   // ng in {0,1}
  int t = tf >> 6, f = tf & 63;
  float pb = preb[t * 64 + f];
  const float* wA = &sW[(t * 128) * 64 + f];
  const float* wB = &sW[(t * 128 + 64) * 64 + f];
  for (int grp = blockIdx.x; grp < N_NODES / 8; grp += gridDim.x) {
    int n0 = grp * 8;
    __syncthreads();
    for (int idx = threadIdx.x; idx < 8 * 64; idx += 256) {
      int nl = idx >> 6, k = idx & 63;
      float v = hin[(size_t)(n0 + nl) * 64 + k];
      if (BN) {
        v = fmaxf(fmaf(v, bnscale[k], bnshift[k]), 0.f);
        h2out[(size_t)(n0 + nl) * 64 + k] = v;
      }
      sh[k * 12 + nl] = v;
    }
    __syncthreads();
    float a0 = pb, a1 = pb, a2 = pb, a3 = pb;
    float b0 = 0, b1 = 0, b2 = 0, b3 = 0;
    const float* hp = &sh[ng * 4];
#pragma unroll 4
    for (int k = 0; k < 64; k++) {
      float4 hv = *(const float4*)&hp[k * 12];
      float wa = wA[k * 64], wb = wB[k * 64];
      a0 = fmaf(hv.x, wa, a0); a1 = fmaf(hv.y, wa, a1);
      a2 = fmaf(hv.z, wa, a2); a3 = fmaf(hv.w, wa, a3);
      b0 = fmaf(hv.x, wb, b0); b1 = fmaf(hv.y, wb, b1);
      b2 = fmaf(hv.z, wb, b2); b3 = fmaf(hv.w, wb, b3);
    }
    size_t nb = (size_t)(n0 + ng * 4);
    hA[nb * 128 + tf] = a0; hA[(nb + 1) * 128 + tf] = a1;
    hA[(nb + 2) * 128 + tf] = a2; hA[(nb + 3) * 128 + tf] = a3;
    hB[nb * 128 + tf] = b0; hB[(nb + 1) * 128 + tf] = b1;
    hB[(nb + 2) * 128 + tf] = b2; hB[(nb + 3) * 128 + tf] = b3;
  }
}

// --------------------------------------------------- fused conv main kernel
// Per block: 4 nodes (one per wave).
// A: CSR edge loop -> sum/sq/min/max in registers (lane owns f=lane, t=0 and 1)
// B: build 13F vector in LDS, node-interleaved [t][f13][node4]
// C: post matmul; wave=rep owns f-quarter for all 4 nodes; postW read once/blk
// D: reduce partials + postb, then fused lin: out = po @ linW + linb
__global__ __launch_bounds__(256) void k_conv(const float* __restrict__ hA,
                                              const float* __restrict__ hB,
                                              const float* __restrict__ hskip,
                                              const int* __restrict__ row_ptr,
                                              const int* __restrict__ csr_src,
                                              const float* __restrict__ postW,
                                              const float* __restrict__ postb,
                                              const float* __restrict__ linW,
                                              const float* __restrict__ linb,
                                              const float* __restrict__ scalars,
                                              float* __restrict__ out) {
  __shared__ float ld13[2 * 832 * 4];   // 26 KB  [t][f13][node]
  __shared__ float lpart[4 * 64 * 4];   // [node][tg][rep]
  __shared__ float lpo[4 * 64];         // [node][tg]
  int w = threadIdx.x >> 6, lane = threadIdx.x & 63;
  int n = blockIdx.x * 4 + w;           // N divisible by 4

  // ---- phase A: aggregation
  size_t hab = (size_t)n * 128;
  float a0 = hA[hab + lane], a1 = hA[hab + 64 + lane];
  int rp0 = row_ptr[n], rp1 = row_ptr[n + 1];
  float s0 = 0, s1 = 0, q0 = 0, q1 = 0;
  float mn0 = INFINITY, mn1 = INFINITY, mx0 = -INFINITY, mx1 = -INFINITY;
  int sid_next = (rp0 < rp1) ? csr_src[rp0] : 0;
  for (int i = rp0; i < rp1; i++) {
    int sid = sid_next;
    if (i + 1 < rp1) sid_next = csr_src[i + 1];
    const float* hb = &hB[(size_t)sid * 128];
    float v0 = hb[lane] + a0;
    float v1 = hb[64 + lane] + a1;
    s0 += v0; q0 = fmaf(v0, v0, q0); mn0 = fminf(mn0, v0); mx0 = fmaxf(mx0, v0);
    s1 += v1; q1 = fmaf(v1, v1, q1); mn1 = fminf(mn1, v1); mx1 = fmaxf(mx1, v1);
  }
  int dg = rp1 - rp0;
  float cnt = (float)(dg > 0 ? dg : 1);
  float inv = 1.0f / cnt;
  float mean0 = s0 * inv, mean1 = s1 * inv;
  float sd0 = sqrtf(fmaxf(q0 * inv - mean0 * mean0, 0.f) + STD_EPS);
  float sd1 = sqrtf(fmaxf(q1 * inv - mean1 * mean1, 0.f) + STD_EPS);
  if (dg == 0) { mn0 = 0; mn1 = 0; mx0 = 0; mx1 = 0; }
  float avg = scalars[1];
  float ldv = logf(cnt + 1.f);
  float sA = ldv / avg, sB = avg / ldv;
  float hs = hskip[(size_t)n * 64 + lane];

  // ---- phase B: write 13F to LDS (node-interleaved)
  {
    float* b0p = &ld13[0];
    float* b1p = &ld13[832 * 4];
    int l4 = lane * 4 + w;
    // tower 0
    b0p[l4] = hs;
    b0p[64 * 4 + l4] = mean0;  b0p[128 * 4 + l4] = mn0;
    b0p[192 * 4 + l4] = mx0;   b0p[256 * 4 + l4] = sd0;
    b0p[320 * 4 + l4] = mean0 * sA; b0p[384 * 4 + l4] = mn0 * sA;
    b0p[448 * 4 + l4] = mx0 * sA;   b0p[512 * 4 + l4] = sd0 * sA;
    b0p[576 * 4 + l4] = mean0 * sB; b0p[640 * 4 + l4] = mn0 * sB;
    b0p[704 * 4 + l4] = mx0 * sB;   b0p[768 * 4 + l4] = sd0 * sB;
    // tower 1
    b1p[l4] = hs;
    b1p[64 * 4 + l4] = mean1;  b1p[128 * 4 + l4] = mn1;
    b1p[192 * 4 + l4] = mx1;   b1p[256 * 4 + l4] = sd1;
    b1p[320 * 4 + l4] = mean1 * sA; b1p[384 * 4 + l4] = mn1 * sA;
    b1p[448 * 4 + l4] = mx1 * sA;   b1p[512 * 4 + l4] = sd1 * sA;
    b1p[576 * 4 + l4] = mean1 * sB; b1p[640 * 4 + l4] = mn1 * sB;
    b1p[704 * 4 + l4] = mx1 * sB;   b1p[768 * 4 + l4] = sd1 * sB;
  }
  __syncthreads();

  // ---- phase C: post matmul, rep = wave covers f-quarter for all 4 nodes
  {
    int tg = lane, t = lane >> 5, g = lane & 31, rep = w;
    const float* pw = &postW[(size_t)t * 832 * 32 + g];
    float c0 = 0, c1 = 0, c2 = 0, c3 = 0;
    int f0 = rep * 208;
#pragma unroll 4
    for (int f = f0; f < f0 + 208; f++) {
      float wv = pw[(size_t)f * 32];
      float4 v4 = *(const float4*)&ld13[(t * 832 + f) << 2];
      c0 = fmaf(v4.x, wv, c0); c1 = fmaf(v4.y, wv, c1);
      c2 = fmaf(v4.z, wv, c2); c3 = fmaf(v4.w, wv, c3);
    }
    lpart[((0 * 64 + tg) << 2) + rep] = c0;
    lpart[((1 * 64 + tg) << 2) + rep] = c1;
    lpart[((2 * 64 + tg) << 2) + rep] = c2;
    lpart[((3 * 64 + tg) << 2) + rep] = c3;
  }
  __syncthreads();

  // ---- phase D: reduce + postb, then lin epilogue
  {
    float4 p = *(const float4*)&lpart[(w * 64 + lane) << 2];
    float po = p.x + p.y + p.z + p.w + postb[lane];
    lpo[w * 64 + lane] = po;
  }
  __syncthreads();
  {
    float acc = linb[lane];
    const float* lw = linW + lane;
    const float* pov = &lpo[w * 64];
#pragma unroll
    for (int i = 0; i < 64; i += 4) {
      float4 p = *(const float4*)&pov[i];
      acc = fmaf(p.x, lw[i * 64], acc);
      acc = fmaf(p.y, lw[(i + 1) * 64], acc);
      acc = fmaf(p.z, lw[(i + 2) * 64], acc);
      acc = fmaf(p.w, lw[(i + 3) * 64], acc);
    }
    out[(size_t)n * 64 + lane] = acc;
  }
}

// ------------------------------------------------------------------ BN stats
__global__ __launch_bounds__(256) void k_bnstats(const float* __restrict__ y,
                                                 float* __restrict__ bnsum,
                                                 float* __restrict__ bnsumsq) {
  __shared__ float r1[256], r2[256];
  int c = threadIdx.x & 63, r = threadIdx.x >> 6;
  float s = 0, q = 0;
  for (int n = blockIdx.x * 4 + r; n < N_NODES; n += gridDim.x * 4) {
    float v = y[(size_t)n * 64 + c];
    s += v; q = fmaf(v, v, q);
  }
  r1[threadIdx.x] = s; r2[threadIdx.x] = q; __syncthreads();
  if (threadIdx.x < 64) {
    s = r1[threadIdx.x] + r1[threadIdx.x + 64] + r1[threadIdx.x + 128] + r1[threadIdx.x + 192];
    q = r2[threadIdx.x] + r2[threadIdx.x + 64] + r2[threadIdx.x + 128] + r2[threadIdx.x + 192];
    atomicAdd(&bnsum[threadIdx.x], s);
    atomicAdd(&bnsumsq[threadIdx.x], q);
  }
}

__global__ void k_bnfin(const float* __restrict__ bnsum, const float* __restrict__ bnsumsq,
                        const float* __restrict__ gamma, const float* __restrict__ beta,
                        float* __restrict__ bnscale, float* __restrict__ bnshift) {
  int c = threadIdx.x;
  if (c < 64) {
    float mu = bnsum[c] * (1.f / N_NODES);
    float var = bnsumsq[c] * (1.f / N_NODES) - mu * mu;
    float sc = gamma[c] / sqrtf(var + BN_EPS);
    bnscale[c] = sc;
    bnshift[c] = fmaf(-mu, sc, beta[c]);
  }
}

// ================================================================== launcher
extern "C" void kernel_launch(void* const* d_in, const int* in_sizes, int n_in,
                              void* d_out, int out_size, void* d_ws, size_t ws_size,
                              hipStream_t stream) {
  const float* x      = (const float*)d_in[0];
  const float* embW   = (const float*)d_in[1];
  const float* embB   = (const float*)d_in[2];
  const float* preW1  = (const float*)d_in[3];
  const float* preb1  = (const float*)d_in[4];
  const float* postW1 = (const float*)d_in[5];
  const float* postb1 = (const float*)d_in[6];
  const float* linW1  = (const float*)d_in[7];
  const float* linb1  = (const float*)d_in[8];
  const float* gamma  = (const float*)d_in[9];
  const float* beta   = (const float*)d_in[10];
  const float* preW2  = (const float*)d_in[11];
  const float* preb2  = (const float*)d_in[12];
  const float* postW2 = (const float*)d_in[13];
  const float* postb2 = (const float*)d_in[14];
  const float* linW2  = (const float*)d_in[15];
  const float* linb2  = (const float*)d_in[16];
  const int*   src    = (const int*)d_in[17];
  const int*   dst    = (const int*)d_in[18];
  float* out = (float*)d_out;

  char* w = (char*)d_ws;
  size_t o = 0;
  int*   deg     = (int*)(w + o);   o += (size_t)N_NODES * 4;
  float* scalars = (float*)(w + o); o += 64;
  float* bnsum   = (float*)(w + o); o += 256;
  float* bnsumsq = (float*)(w + o); o += 256;
  float* bnscale = (float*)(w + o); o += 256;
  float* bnshift = (float*)(w + o); o += 256;
  size_t zero_len = o;
  o = (o + 255) & ~(size_t)255;
  int* partials = (int*)(w + o);  o += 256;
  int* row_ptr  = (int*)(w + o);  o += (size_t)(N_NODES + 1) * 4; o = (o + 255) & ~(size_t)255;
  int* cursor   = (int*)(w + o);  o += (size_t)N_NODES * 4;       o = (o + 255) & ~(size_t)255;
  int* csr      = (int*)(w + o);  o += (size_t)E_EDGES * 4;       o = (o + 255) & ~(size_t)255;
  float* h1 = (float*)(w + o); o += (size_t)N_NODES * 64 * 4;
  float* y1 = (float*)(w + o); o += (size_t)N_NODES * 64 * 4;
  float* h2 = (float*)(w + o); o += (size_t)N_NODES * 64 * 4;
  float* hA = (float*)(w + o); o += (size_t)N_NODES * 128 * 4;
  float* hB = (float*)(w + o); o += (size_t)N_NODES * 128 * 4;

  hipMemsetAsync(w, 0, zero_len, stream);

  const int NBLK_SCAN = (N_NODES + 1023) / 1024;   // 49
  k_hist<<<(E_EDGES + 255) / 256, 256, 0, stream>>>(dst, deg);
  k_sumlog<<<(N_NODES + 255) / 256, 256, 0, stream>>>(deg, scalars);
  k_scan_part<<<NBLK_SCAN, 256, 0, stream>>>(deg, partials);
  k_scan_mid<<<1, 64, 0, stream>>>(partials, NBLK_SCAN, scalars);
  k_scan_final<<<NBLK_SCAN, 256, 0, stream>>>(deg, partials, row_ptr, cursor);
  k_scatter<<<(E_EDGES + 255) / 256, 256, 0, stream>>>(src, dst, cursor, csr);

  k_embed<<<768, 256, 0, stream>>>(x, embW, embB, h1);

  // ----- layer 1
  k_preab<false><<<512, 256, 0, stream>>>(h1, preW1, preb1, nullptr, nullptr, nullptr, hA, hB);
  k_conv<<<N_NODES / 4, 256, 0, stream>>>(hA, hB, h1, row_ptr, csr,
                                          postW1, postb1, linW1, linb1, scalars, y1);
  // ----- batchnorm
  k_bnstats<<<256, 256, 0, stream>>>(y1, bnsum, bnsumsq);
  k_bnfin<<<1, 64, 0, stream>>>(bnsum, bnsumsq, gamma, beta, bnscale, bnshift);

  // ----- layer 2 (BN+relu fused into staging; h2 materialized for skip)
  k_preab<true><<<512, 256, 0, stream>>>(y1, preW2, preb2, bnscale, bnshift, h2, hA, hB);
  k_conv<<<N_NODES / 4, 256, 0, stream>>>(hA, hB, h2, row_ptr, csr,
                                          postW2, postb2, linW2, linb2, scalars, out);
}

// Round 2
// 682.947 us; speedup vs baseline: 1.2760x; 1.2760x over previous
//
#include <hip/hip_runtime.h>

#define N_NODES 50000
#define E_EDGES 800000
#define IN_F    128
#define H_F     64
#define STD_EPS 1e-5f
#define BN_EPS  1e-5f

// ---------------------------------------------------------------- degree hist
__global__ __launch_bounds__(256) void k_hist(const int* __restrict__ dst,
                                              int* __restrict__ deg) {
  int e = blockIdx.x * 256 + threadIdx.x;
  if (e < E_EDGES) atomicAdd(&deg[dst[e]], 1);
}

// ------------------------------------------------------- sum of log(deg+1)
__global__ __launch_bounds__(256) void k_sumlog(const int* __restrict__ deg,
                                                float* __restrict__ scalars) {
  __shared__ float red[256];
  int i = blockIdx.x * 256 + threadIdx.x;
  float v = 0.f;
  if (i < N_NODES) v = logf((float)deg[i] + 1.0f);
  red[threadIdx.x] = v; __syncthreads();
  for (int s = 128; s > 0; s >>= 1) {
    if (threadIdx.x < s) red[threadIdx.x] += red[threadIdx.x + s];
    __syncthreads();
  }
  if (threadIdx.x == 0) atomicAdd(&scalars[0], red[0]);
}

// ------------------------------------------------------------- scan (3-phase)
__global__ __launch_bounds__(256) void k_scan_part(const int* __restrict__ deg,
                                                   int* __restrict__ partials) {
  __shared__ int red[256];
  int base = blockIdx.x * 1024;
  int s = 0;
  for (int j = threadIdx.x; j < 1024; j += 256) {
    int i = base + j;
    if (i < N_NODES) s += deg[i];
  }
  red[threadIdx.x] = s; __syncthreads();
  for (int st = 128; st > 0; st >>= 1) {
    if (threadIdx.x < st) red[threadIdx.x] += red[threadIdx.x + st];
    __syncthreads();
  }
  if (threadIdx.x == 0) partials[blockIdx.x] = red[0];
}

__global__ void k_scan_mid(int* __restrict__ partials, int nblk,
                           float* __restrict__ scalars) {
  if (threadIdx.x == 0) {
    int run = 0;
    for (int b = 0; b < nblk; b++) { int v = partials[b]; partials[b] = run; run += v; }
    scalars[1] = scalars[0] / (float)N_NODES;   // avg_log
  }
}

__global__ __launch_bounds__(256) void k_scan_final(const int* __restrict__ deg,
                                                    const int* __restrict__ partials,
                                                    int* __restrict__ row_ptr,
                                                    int* __restrict__ cursor) {
  __shared__ int ts[256];
  int base = blockIdx.x * 1024 + threadIdx.x * 4;
  int d[4]; int s = 0;
#pragma unroll
  for (int j = 0; j < 4; j++) {
    int i = base + j;
    d[j] = (i < N_NODES) ? deg[i] : 0;
    s += d[j];
  }
  ts[threadIdx.x] = s; __syncthreads();
  for (int off = 1; off < 256; off <<= 1) {
    int t = (threadIdx.x >= off) ? ts[threadIdx.x - off] : 0;
    __syncthreads();
    ts[threadIdx.x] += t;
    __syncthreads();
  }
  int excl = (threadIdx.x > 0) ? ts[threadIdx.x - 1] : 0;
  int run = partials[blockIdx.x] + excl;
#pragma unroll
  for (int j = 0; j < 4; j++) {
    int i = base + j;
    if (i < N_NODES) { row_ptr[i] = run; cursor[i] = run; run += d[j]; }
  }
  if (blockIdx.x == 0 && threadIdx.x == 0) row_ptr[N_NODES] = E_EDGES;
}

// ------------------------------------------------------------------- scatter
__global__ __launch_bounds__(256) void k_scatter(const int* __restrict__ src,
                                                 const int* __restrict__ dst,
                                                 int* __restrict__ cursor,
                                                 int* __restrict__ csr_src) {
  int e = blockIdx.x * 256 + threadIdx.x;
  if (e < E_EDGES) {
    int d = dst[e];
    int p = atomicAdd(&cursor[d], 1);
    csr_src[p] = src[e];
  }
}

// --------------------------------------------------------------------- embed
__global__ __launch_bounds__(256) void k_embed(const float* __restrict__ x,
                                               const float* __restrict__ W,
                                               const float* __restrict__ bias,
                                               float* __restrict__ h) {
  __shared__ float sW[IN_F * 64];    // 32 KB
  __shared__ float sx[IN_F * 20];    // x_T[k][16+pad4]
  for (int i = threadIdx.x; i < IN_F * 64; i += 256) sW[i] = W[i];
  int j = threadIdx.x & 63, ng = threadIdx.x >> 6;
  float bj = bias[j];
  for (int grp = blockIdx.x; grp < N_NODES / 16; grp += gridDim.x) {
    int n0 = grp * 16;
    __syncthreads();
    for (int idx = threadIdx.x; idx < 16 * IN_F; idx += 256) {
      int nl = idx >> 7, k = idx & 127;
      sx[k * 20 + nl] = x[(size_t)(n0 + nl) * IN_F + k];
    }
    __syncthreads();
    float a0 = bj, a1 = bj, a2 = bj, a3 = bj;
    const float* xp = &sx[ng * 4];
#pragma unroll 4
    for (int k = 0; k < IN_F; k++) {
      float4 xv = *(const float4*)&xp[k * 20];
      float w = sW[k * 64 + j];
      a0 = fmaf(xv.x, w, a0); a1 = fmaf(xv.y, w, a1);
      a2 = fmaf(xv.z, w, a2); a3 = fmaf(xv.w, w, a3);
    }
    size_t ob = (size_t)(n0 + ng * 4) * 64 + j;
    h[ob] = a0; h[ob + 64] = a1; h[ob + 128] = a2; h[ob + 192] = a3;
  }
}

// ------------------------------------------------------------------ pre A/B
// hA[n, t*64+f] = preb[t,f] + sum_k h[n,k]*preW[t,k,f]       (bias folded)
// hB[n, t*64+f] =             sum_k h[n,k]*preW[t,64+k,f]
// 16 nodes/group; ng in {0,1} handles 8 nodes as 2 float4s.
template <bool BN>
__global__ __launch_bounds__(256) void k_preab(const float* __restrict__ hin,
                                               const float* __restrict__ preW,
                                               const float* __restrict__ preb,
                                               const float* __restrict__ bnscale,
                                               const float* __restrict__ bnshift,
                                               float* __restrict__ h2out,
                                               float* __restrict__ hA,
                                               float* __restrict__ hB) {
  __shared__ float sW[2 * 128 * 64];   // 64 KB
  __shared__ float sh[64 * 20];        // h_T[k][16+pad4]
  for (int i = threadIdx.x; i < 2 * 128 * 64; i += 256) sW[i] = preW[i];
  int tf = threadIdx.x & 127, ng = threadIdx.x >> 7;
  int t = tf >> 6, f = tf & 63;
  float pb = preb[t * 64 + f];
  const float* wA = &sW[(t * 128) * 64 + f];
  const float* wB = &sW[(t * 128 + 64) * 64 + f];
  for (int grp = blockIdx.x; grp < N_NODES / 16; grp += gridDim.x) {
    int n0 = grp * 16;
    __syncthreads();
    for (int idx = threadIdx.x; idx < 16 * 64; idx += 256) {
      int nl = idx >> 6, k = idx & 63;
      float v = hin[(size_t)(n0 + nl) * 64 + k];
      if (BN) {
        v = fmaxf(fmaf(v, bnscale[k], bnshift[k]), 0.f);
        h2out[(size_t)(n0 + nl) * 64 + k] = v;
      }
      sh[k * 20 + nl] = v;
    }
    __syncthreads();
    float a0=pb,a1=pb,a2=pb,a3=pb,a4=pb,a5=pb,a6=pb,a7=pb;
    float b0=0,b1=0,b2=0,b3=0,b4=0,b5=0,b6=0,b7=0;
    const float* hp = &sh[ng * 8];
#pragma unroll 4
    for (int k = 0; k < 64; k++) {
      float4 h0 = *(const float4*)&hp[k * 20];
      float4 h1 = *(const float4*)&hp[k * 20 + 4];
      float wa = wA[k * 64], wb = wB[k * 64];
      a0 = fmaf(h0.x, wa, a0); a1 = fmaf(h0.y, wa, a1);
      a2 = fmaf(h0.z, wa, a2); a3 = fmaf(h0.w, wa, a3);
      a4 = fmaf(h1.x, wa, a4); a5 = fmaf(h1.y, wa, a5);
      a6 = fmaf(h1.z, wa, a6); a7 = fmaf(h1.w, wa, a7);
      b0 = fmaf(h0.x, wb, b0); b1 = fmaf(h0.y, wb, b1);
      b2 = fmaf(h0.z, wb, b2); b3 = fmaf(h0.w, wb, b3);
      b4 = fmaf(h1.x, wb, b4); b5 = fmaf(h1.y, wb, b5);
      b6 = fmaf(h1.z, wb, b6); b7 = fmaf(h1.w, wb, b7);
    }
    size_t nb = (size_t)(n0 + ng * 8);
    hA[nb * 128 + tf] = a0;        hB[nb * 128 + tf] = b0;
    hA[(nb+1) * 128 + tf] = a1;    hB[(nb+1) * 128 + tf] = b1;
    hA[(nb+2) * 128 + tf] = a2;    hB[(nb+2) * 128 + tf] = b2;
    hA[(nb+3) * 128 + tf] = a3;    hB[(nb+3) * 128 + tf] = b3;
    hA[(nb+4) * 128 + tf] = a4;    hB[(nb+4) * 128 + tf] = b4;
    hA[(nb+5) * 128 + tf] = a5;    hB[(nb+5) * 128 + tf] = b5;
    hA[(nb+6) * 128 + tf] = a6;    hB[(nb+6) * 128 + tf] = b6;
    hA[(nb+7) * 128 + tf] = a7;    hB[(nb+7) * 128 + tf] = b7;
  }
}

// --------------------------------------------------- fused conv main kernel
// Per block: 4 nodes (one per wave).
// Lane map (phase A/B): t = lane>>5, f = {2*(lane&31), +1}  -> one wave reads
// a whole 512B hB row per edge with ONE global_load_dwordx2.
// LDS: single 26.6KB buffer; lpart/lpo aliased into it after phase C reads.
__global__ __launch_bounds__(256, 6) void k_conv(const float* __restrict__ hA,
                                                 const float* __restrict__ hB,
                                                 const float* __restrict__ hskip,
                                                 const int* __restrict__ row_ptr,
                                                 const int* __restrict__ csr_src,
                                                 const float* __restrict__ postW,
                                                 const float* __restrict__ postb,
                                                 const float* __restrict__ linW,
                                                 const float* __restrict__ linb,
                                                 const float* __restrict__ scalars,
                                                 float* __restrict__ out) {
  __shared__ float smem[2 * 832 * 4];   // 26624 B: ld13 [t][f13][node4]
  int w = threadIdx.x >> 6, lane = threadIdx.x & 63;
  int n = blockIdx.x * 4 + w;           // N divisible by 4
  int t = lane >> 5, fb = (lane & 31) * 2;
  int off = t * 64 + fb;

  // ---- phase A: aggregation (2-edge unrolled, dual accumulator sets)
  float2 a = *(const float2*)&hA[(size_t)n * 128 + off];
  int rp0 = __builtin_amdgcn_readfirstlane(row_ptr[n]);
  int rp1 = __builtin_amdgcn_readfirstlane(row_ptr[n + 1]);
  float sx0=0,sy0=0,qx0=0,qy0=0, sx1=0,sy1=0,qx1=0,qy1=0;
  float mnx0=INFINITY,mny0=INFINITY,mxx0=-INFINITY,mxy0=-INFINITY;
  float mnx1=INFINITY,mny1=INFINITY,mxx1=-INFINITY,mxy1=-INFINITY;
  int i = rp0;
  if ((rp1 - rp0) & 1) {
    int sid = csr_src[i]; i++;
    float2 v = *(const float2*)&hB[(size_t)sid * 128 + off];
    float vx = v.x + a.x, vy = v.y + a.y;
    sx0 += vx; sy0 += vy; qx0 = fmaf(vx,vx,qx0); qy0 = fmaf(vy,vy,qy0);
    mnx0 = fminf(mnx0,vx); mny0 = fminf(mny0,vy);
    mxx0 = fmaxf(mxx0,vx); mxy0 = fmaxf(mxy0,vy);
  }
  if (i < rp1) {
    int sa = csr_src[i], sb = csr_src[i + 1];
    while (true) {
      float2 va = *(const float2*)&hB[(size_t)sa * 128 + off];
      float2 vb = *(const float2*)&hB[(size_t)sb * 128 + off];
      i += 2;
      bool more = (i < rp1);
      if (more) { sa = csr_src[i]; sb = csr_src[i + 1]; }
      float vax = va.x + a.x, vay = va.y + a.y;
      float vbx = vb.x + a.x, vby = vb.y + a.y;
      sx0 += vax; sy0 += vay; qx0 = fmaf(vax,vax,qx0); qy0 = fmaf(vay,vay,qy0);
      mnx0 = fminf(mnx0,vax); mny0 = fminf(mny0,vay);
      mxx0 = fmaxf(mxx0,vax); mxy0 = fmaxf(mxy0,vay);
      sx1 += vbx; sy1 += vby; qx1 = fmaf(vbx,vbx,qx1); qy1 = fmaf(vby,vby,qy1);
      mnx1 = fminf(mnx1,vbx); mny1 = fminf(mny1,vby);
      mxx1 = fmaxf(mxx1,vbx); mxy1 = fmaxf(mxy1,vby);
      if (!more) break;
    }
  }
  int dg = rp1 - rp0;
  float cnt = (float)(dg > 0 ? dg : 1);
  float inv = 1.0f / cnt;
  float meanx = (sx0 + sx1) * inv, meany = (sy0 + sy1) * inv;
  float qx = qx0 + qx1, qy = qy0 + qy1;
  float sdx = sqrtf(fmaxf(qx * inv - meanx * meanx, 0.f) + STD_EPS);
  float sdy = sqrtf(fmaxf(qy * inv - meany * meany, 0.f) + STD_EPS);
  float mnx = fminf(mnx0, mnx1), mny = fminf(mny0, mny1);
  float mxx = fmaxf(mxx0, mxx1), mxy = fmaxf(mxy0, mxy1);
  if (dg == 0) { mnx = 0; mny = 0; mxx = 0; mxy = 0; }
  float avg = scalars[1];
  float ldv = logf(cnt + 1.f);
  float sA = ldv / avg, sB = avg / ldv;
  float2 hsv = *(const float2*)&hskip[(size_t)n * 64 + fb];

  // ---- phase B: write 13F to LDS [t][feat13*64+f][node4]
  {
    float* bp = &smem[t * 3328 + fb * 4 + w];
    bp[0]    = hsv.x;       bp[4]    = hsv.y;
    bp[256]  = meanx;       bp[260]  = meany;
    bp[512]  = mnx;         bp[516]  = mny;
    bp[768]  = mxx;         bp[772]  = mxy;
    bp[1024] = sdx;         bp[1028] = sdy;
    bp[1280] = meanx * sA;  bp[1284] = meany * sA;
    bp[1536] = mnx * sA;    bp[1540] = mny * sA;
    bp[1792] = mxx * sA;    bp[1796] = mxy * sA;
    bp[2048] = sdx * sA;    bp[2052] = sdy * sA;
    bp[2304] = meanx * sB;  bp[2308] = meany * sB;
    bp[2560] = mnx * sB;    bp[2564] = mny * sB;
    bp[2816] = mxx * sB;    bp[2820] = mxy * sB;
    bp[3072] = sdx * sB;    bp[3076] = sdy * sB;
  }
  __syncthreads();

  // ---- phase C: post matmul; wave covers one f-quarter for all 4 nodes
  float c0 = 0, c1 = 0, c2 = 0, c3 = 0;
  {
    int tC = lane >> 5, g = lane & 31, rep = w;
    const float* pw = &postW[(size_t)tC * 832 * 32 + (size_t)(rep * 208) * 32 + g];
    const float* lp = &smem[(tC * 832 + rep * 208) * 4];
    for (int f = 0; f < 208; f += 4) {
      float w0 = pw[0], w1 = pw[32], w2 = pw[64], w3 = pw[96];
      float4 v0 = *(const float4*)(lp + 0);
      float4 v1 = *(const float4*)(lp + 4);
      float4 v2 = *(const float4*)(lp + 8);
      float4 v3 = *(const float4*)(lp + 12);
      c0 = fmaf(v0.x, w0, c0); c1 = fmaf(v0.y, w0, c1);
      c2 = fmaf(v0.z, w0, c2); c3 = fmaf(v0.w, w0, c3);
      c0 = fmaf(v1.x, w1, c0); c1 = fmaf(v1.y, w1, c1);
      c2 = fmaf(v1.z, w1, c2); c3 = fmaf(v1.w, w1, c3);
      c0 = fmaf(v2.x, w2, c0); c1 = fmaf(v2.y, w2, c1);
      c2 = fmaf(v2.z, w2, c2); c3 = fmaf(v2.w, w2, c3);
      c0 = fmaf(v3.x, w3, c0); c1 = fmaf(v3.y, w3, c1);
      c2 = fmaf(v3.z, w3, c2); c3 = fmaf(v3.w, w3, c3);
      pw += 128; lp += 16;
    }
  }
  __syncthreads();   // all ld13 reads done -> safe to alias

  // ---- write partials into aliased region: lpart = smem[0..1023]
  {
    int tg = lane, rep = w;
    smem[((0 * 64 + tg) << 2) + rep] = c0;
    smem[((1 * 64 + tg) << 2) + rep] = c1;
    smem[((2 * 64 + tg) << 2) + rep] = c2;
    smem[((3 * 64 + tg) << 2) + rep] = c3;
  }
  __syncthreads();

  // ---- phase D: reduce + postb -> lpo = smem[1024..1279]
  {
    float4 p = *(const float4*)&smem[(w * 64 + lane) << 2];
    float po = p.x + p.y + p.z + p.w + postb[lane];
    smem[1024 + w * 64 + lane] = po;
  }
  __syncthreads();

  // ---- lin epilogue
  {
    float acc = linb[lane];
    const float* lw = linW + lane;
    const float* pov = &smem[1024 + w * 64];
#pragma unroll
    for (int i2 = 0; i2 < 64; i2 += 4) {
      float4 p = *(const float4*)&pov[i2];
      acc = fmaf(p.x, lw[i2 * 64], acc);
      acc = fmaf(p.y, lw[(i2 + 1) * 64], acc);
      acc = fmaf(p.z, lw[(i2 + 2) * 64], acc);
      acc = fmaf(p.w, lw[(i2 + 3) * 64], acc);
    }
    out[(size_t)n * 64 + lane] = acc;
  }
}

// ------------------------------------------------------------------ BN stats
__global__ __launch_bounds__(256) void k_bnstats(const float* __restrict__ y,
                                                 float* __restrict__ bnsum,
                                                 float* __restrict__ bnsumsq) {
  __shared__ float r1[256], r2[256];
  int c = threadIdx.x & 63, r = threadIdx.x >> 6;
  float s = 0, q = 0;
  for (int n = blockIdx.x * 4 + r; n < N_NODES; n += gridDim.x * 4) {
    float v = y[(size_t)n * 64 + c];
    s += v; q = fmaf(v, v, q);
  }
  r1[threadIdx.x] = s; r2[threadIdx.x] = q; __syncthreads();
  if (threadIdx.x < 64) {
    s = r1[threadIdx.x] + r1[threadIdx.x + 64] + r1[threadIdx.x + 128] + r1[threadIdx.x + 192];
    q = r2[threadIdx.x] + r2[threadIdx.x + 64] + r2[threadIdx.x + 128] + r2[threadIdx.x + 192];
    atomicAdd(&bnsum[threadIdx.x], s);
    atomicAdd(&bnsumsq[threadIdx.x], q);
  }
}

__global__ void k_bnfin(const float* __restrict__ bnsum, const float* __restrict__ bnsumsq,
                        const float* __restrict__ gamma, const float* __restrict__ beta,
                        float* __restrict__ bnscale, float* __restrict__ bnshift) {
  int c = threadIdx.x;
  if (c < 64) {
    float mu = bnsum[c] * (1.f / N_NODES);
    float var = bnsumsq[c] * (1.f / N_NODES) - mu * mu;
    float sc = gamma[c] / sqrtf(var + BN_EPS);
    bnscale[c] = sc;
    bnshift[c] = fmaf(-mu, sc, beta[c]);
  }
}

// ================================================================== launcher
extern "C" void kernel_launch(void* const* d_in, const int* in_sizes, int n_in,
                              void* d_out, int out_size, void* d_ws, size_t ws_size,
                              hipStream_t stream) {
  const float* x      = (const float*)d_in[0];
  const float* embW   = (const float*)d_in[1];
  const float* embB   = (const float*)d_in[2];
  const float* preW1  = (const float*)d_in[3];
  const float* preb1  = (const float*)d_in[4];
  const float* postW1 = (const float*)d_in[5];
  const float* postb1 = (const float*)d_in[6];
  const float* linW1  = (const float*)d_in[7];
  const float* linb1  = (const float*)d_in[8];
  const float* gamma  = (const float*)d_in[9];
  const float* beta   = (const float*)d_in[10];
  const float* preW2  = (const float*)d_in[11];
  const float* preb2  = (const float*)d_in[12];
  const float* postW2 = (const float*)d_in[13];
  const float* postb2 = (const float*)d_in[14];
  const float* linW2  = (const float*)d_in[15];
  const float* linb2  = (const float*)d_in[16];
  const int*   src    = (const int*)d_in[17];
  const int*   dst    = (const int*)d_in[18];
  float* out = (float*)d_out;

  char* w = (char*)d_ws;
  size_t o = 0;
  int*   deg     = (int*)(w + o);   o += (size_t)N_NODES * 4;
  float* scalars = (float*)(w + o); o += 64;
  float* bnsum   = (float*)(w + o); o += 256;
  float* bnsumsq = (float*)(w + o); o += 256;
  float* bnscale = (float*)(w + o); o += 256;
  float* bnshift = (float*)(w + o); o += 256;
  size_t zero_len = o;
  o = (o + 255) & ~(size_t)255;
  int* partials = (int*)(w + o);  o += 256;
  int* row_ptr  = (int*)(w + o);  o += (size_t)(N_NODES + 1) * 4; o = (o + 255) & ~(size_t)255;
  int* cursor   = (int*)(w + o);  o += (size_t)N_NODES * 4;       o = (o + 255) & ~(size_t)255;
  int* csr      = (int*)(w + o);  o += (size_t)E_EDGES * 4;       o = (o + 255) & ~(size_t)255;
  float* h1 = (float*)(w + o); o += (size_t)N_NODES * 64 * 4;
  float* y1 = (float*)(w + o); o += (size_t)N_NODES * 64 * 4;
  float* h2 = (float*)(w + o); o += (size_t)N_NODES * 64 * 4;
  float* hA = (float*)(w + o); o += (size_t)N_NODES * 128 * 4;
  float* hB = (float*)(w + o); o += (size_t)N_NODES * 128 * 4;

  hipMemsetAsync(w, 0, zero_len, stream);

  const int NBLK_SCAN = (N_NODES + 1023) / 1024;   // 49
  k_hist<<<(E_EDGES + 255) / 256, 256, 0, stream>>>(dst, deg);
  k_sumlog<<<(N_NODES + 255) / 256, 256, 0, stream>>>(deg, scalars);
  k_scan_part<<<NBLK_SCAN, 256, 0, stream>>>(deg, partials);
  k_scan_mid<<<1, 64, 0, stream>>>(partials, NBLK_SCAN, scalars);
  k_scan_final<<<NBLK_SCAN, 256, 0, stream>>>(deg, partials, row_ptr, cursor);
  k_scatter<<<(E_EDGES + 255) / 256, 256, 0, stream>>>(src, dst, cursor, csr);

  k_embed<<<768, 256, 0, stream>>>(x, embW, embB, h1);

  // ----- layer 1
  k_preab<false><<<512, 256, 0, stream>>>(h1, preW1, preb1, nullptr, nullptr, nullptr, hA, hB);
  k_conv<<<N_NODES / 4, 256, 0, stream>>>(hA, hB, h1, row_ptr, csr,
                                          postW1, postb1, linW1, linb1, scalars, y1);
  // ----- batchnorm
  k_bnstats<<<256, 256, 0, stream>>>(y1, bnsum, bnsumsq);
  k_bnfin<<<1, 64, 0, stream>>>(bnsum, bnsumsq, gamma, beta, bnscale, bnshift);

  // ----- layer 2 (BN+relu fused into staging; h2 materialized for skip)
  k_preab<true><<<512, 256, 0, stream>>>(y1, preW2, preb2, bnscale, bnshift, h2, hA, hB);
  k_conv<<<N_NODES / 4, 256, 0, stream>>>(hA, hB, h2, row_ptr, csr,
                                          postW2, postb2, linW2, linb2, scalars, out);
}

// Round 3
// 647.415 us; speedup vs baseline: 1.3461x; 1.0549x over previous
//
#include <hip/hip_runtime.h>

#define N_NODES 50000
#define E_EDGES 800000
#define IN_F    128
#define H_F     64
#define STD_EPS 1e-5f
#define BN_EPS  1e-5f

// ---------------------------------------------------------------- degree hist
__global__ __launch_bounds__(256) void k_hist(const int* __restrict__ dst,
                                              int* __restrict__ deg) {
  int e = blockIdx.x * 256 + threadIdx.x;
  if (e < E_EDGES) atomicAdd(&deg[dst[e]], 1);
}

// ------------------------------------------------------- sum of log(deg+1)
__global__ __launch_bounds__(256) void k_sumlog(const int* __restrict__ deg,
                                                float* __restrict__ scalars) {
  __shared__ float red[256];
  int i = blockIdx.x * 256 + threadIdx.x;
  float v = 0.f;
  if (i < N_NODES) v = logf((float)deg[i] + 1.0f);
  red[threadIdx.x] = v; __syncthreads();
  for (int s = 128; s > 0; s >>= 1) {
    if (threadIdx.x < s) red[threadIdx.x] += red[threadIdx.x + s];
    __syncthreads();
  }
  if (threadIdx.x == 0) atomicAdd(&scalars[0], red[0]);
}

// ------------------------------------------------------------- scan (3-phase)
__global__ __launch_bounds__(256) void k_scan_part(const int* __restrict__ deg,
                                                   int* __restrict__ partials) {
  __shared__ int red[256];
  int base = blockIdx.x * 1024;
  int s = 0;
  for (int j = threadIdx.x; j < 1024; j += 256) {
    int i = base + j;
    if (i < N_NODES) s += deg[i];
  }
  red[threadIdx.x] = s; __syncthreads();
  for (int st = 128; st > 0; st >>= 1) {
    if (threadIdx.x < st) red[threadIdx.x] += red[threadIdx.x + st];
    __syncthreads();
  }
  if (threadIdx.x == 0) partials[blockIdx.x] = red[0];
}

__global__ void k_scan_mid(int* __restrict__ partials, int nblk,
                           float* __restrict__ scalars) {
  if (threadIdx.x == 0) {
    int run = 0;
    for (int b = 0; b < nblk; b++) { int v = partials[b]; partials[b] = run; run += v; }
    scalars[1] = scalars[0] / (float)N_NODES;   // avg_log
  }
}

__global__ __launch_bounds__(256) void k_scan_final(const int* __restrict__ deg,
                                                    const int* __restrict__ partials,
                                                    int* __restrict__ row_ptr,
                                                    int* __restrict__ cursor) {
  __shared__ int ts[256];
  int base = blockIdx.x * 1024 + threadIdx.x * 4;
  int d[4]; int s = 0;
#pragma unroll
  for (int j = 0; j < 4; j++) {
    int i = base + j;
    d[j] = (i < N_NODES) ? deg[i] : 0;
    s += d[j];
  }
  ts[threadIdx.x] = s; __syncthreads();
  for (int off = 1; off < 256; off <<= 1) {
    int t = (threadIdx.x >= off) ? ts[threadIdx.x - off] : 0;
    __syncthreads();
    ts[threadIdx.x] += t;
    __syncthreads();
  }
  int excl = (threadIdx.x > 0) ? ts[threadIdx.x - 1] : 0;
  int run = partials[blockIdx.x] + excl;
#pragma unroll
  for (int j = 0; j < 4; j++) {
    int i = base + j;
    if (i < N_NODES) { row_ptr[i] = run; cursor[i] = run; run += d[j]; }
  }
  if (blockIdx.x == 0 && threadIdx.x == 0) row_ptr[N_NODES] = E_EDGES;
}

// ------------------------------------------------------------------- scatter
__global__ __launch_bounds__(256) void k_scatter(const int* __restrict__ src,
                                                 const int* __restrict__ dst,
                                                 int* __restrict__ cursor,
                                                 int* __restrict__ csr_src) {
  int e = blockIdx.x * 256 + threadIdx.x;
  if (e < E_EDGES) {
    int d = dst[e];
    int p = atomicAdd(&cursor[d], 1);
    csr_src[p] = src[e];
  }
}

// --------------------------------------------------------------------- embed
__global__ __launch_bounds__(256) void k_embed(const float* __restrict__ x,
                                               const float* __restrict__ W,
                                               const float* __restrict__ bias,
                                               float* __restrict__ h) {
  __shared__ float sW[IN_F * 64];    // 32 KB
  __shared__ float sx[IN_F * 20];    // x_T[k][16+pad4]
  for (int i = threadIdx.x; i < IN_F * 64; i += 256) sW[i] = W[i];
  int j = threadIdx.x & 63, ng = threadIdx.x >> 6;
  float bj = bias[j];
  for (int grp = blockIdx.x; grp < N_NODES / 16; grp += gridDim.x) {
    int n0 = grp * 16;
    __syncthreads();
    for (int idx = threadIdx.x; idx < 16 * IN_F; idx += 256) {
      int nl = idx >> 7, k = idx & 127;
      sx[k * 20 + nl] = x[(size_t)(n0 + nl) * IN_F + k];
    }
    __syncthreads();
    float a0 = bj, a1 = bj, a2 = bj, a3 = bj;
    const float* xp = &sx[ng * 4];
#pragma unroll 4
    for (int k = 0; k < IN_F; k++) {
      float4 xv = *(const float4*)&xp[k * 20];
      float w = sW[k * 64 + j];
      a0 = fmaf(xv.x, w, a0); a1 = fmaf(xv.y, w, a1);
      a2 = fmaf(xv.z, w, a2); a3 = fmaf(xv.w, w, a3);
    }
    size_t ob = (size_t)(n0 + ng * 4) * 64 + j;
    h[ob] = a0; h[ob + 64] = a1; h[ob + 128] = a2; h[ob + 192] = a3;
  }
}

// ------------------------------------------------------------------ pre A/B
// One TOWER per block (t = blockIdx.x & 1): LDS 32KB -> 4 blocks/CU.
// hA[n, t*64+f] = preb[t,f] + sum_k h[n,k]*preW[t,k,f]       (bias folded)
// hB[n, t*64+f] =             sum_k h[n,k]*preW[t,64+k,f]
template <bool BN>
__global__ __launch_bounds__(256) void k_preab(const float* __restrict__ hin,
                                               const float* __restrict__ preW,
                                               const float* __restrict__ preb,
                                               const float* __restrict__ bnscale,
                                               const float* __restrict__ bnshift,
                                               float* __restrict__ h2out,
                                               float* __restrict__ hA,
                                               float* __restrict__ hB) {
  __shared__ float sW[128 * 64];   // 32 KB (this tower)
  __shared__ float sh[64 * 20];    // h_T[k][16+pad4]
  int t = blockIdx.x & 1;
  const float* Wsrc = preW + (size_t)t * 128 * 64;
  for (int i = threadIdx.x; i < 128 * 64; i += 256) sW[i] = Wsrc[i];
  int f = threadIdx.x & 63, ng = threadIdx.x >> 6;   // ng in 0..3 -> 4 nodes each
  float pb = preb[t * 64 + f];
  const float* wA = &sW[f];
  const float* wB = &sW[64 * 64 + f];
  int nblk2 = gridDim.x >> 1;
  for (int grp = blockIdx.x >> 1; grp < N_NODES / 16; grp += nblk2) {
    int n0 = grp * 16;
    __syncthreads();
    for (int idx = threadIdx.x; idx < 16 * 64; idx += 256) {
      int nl = idx >> 6, k = idx & 63;
      float v = hin[(size_t)(n0 + nl) * 64 + k];
      if (BN) {
        v = fmaxf(fmaf(v, bnscale[k], bnshift[k]), 0.f);
        if (t == 0) h2out[(size_t)(n0 + nl) * 64 + k] = v;
      }
      sh[k * 20 + nl] = v;
    }
    __syncthreads();
    float a0 = pb, a1 = pb, a2 = pb, a3 = pb;
    float b0 = 0, b1 = 0, b2 = 0, b3 = 0;
    const float* hp = &sh[ng * 4];
#pragma unroll 4
    for (int k = 0; k < 64; k++) {
      float4 hv = *(const float4*)&hp[k * 20];
      float wa = wA[k * 64], wb = wB[k * 64];
      a0 = fmaf(hv.x, wa, a0); a1 = fmaf(hv.y, wa, a1);
      a2 = fmaf(hv.z, wa, a2); a3 = fmaf(hv.w, wa, a3);
      b0 = fmaf(hv.x, wb, b0); b1 = fmaf(hv.y, wb, b1);
      b2 = fmaf(hv.z, wb, b2); b3 = fmaf(hv.w, wb, b3);
    }
    size_t nb = (size_t)(n0 + ng * 4);
    int tf = t * 64 + f;
    hA[nb * 128 + tf] = a0;          hB[nb * 128 + tf] = b0;
    hA[(nb + 1) * 128 + tf] = a1;    hB[(nb + 1) * 128 + tf] = b1;
    hA[(nb + 2) * 128 + tf] = a2;    hB[(nb + 2) * 128 + tf] = b2;
    hA[(nb + 3) * 128 + tf] = a3;    hB[(nb + 3) * 128 + tf] = b3;
  }
}

// --------------------------------------------------- fused conv main kernel
// Per block: 4 nodes (one per wave).
// Phase A: 4-edge unroll -> 4 gathers in flight; masked parallel tail.
// LDS layout (node-major): smem[(t*13+feat)*256 + node*64 + hf]
//   -> phase B: 13 ds_write_b64, lane-stride-2 (conflict-free)
//   -> phase C: b128 broadcast reads over hf (conflict-free)
__global__ __launch_bounds__(256, 6) void k_conv(const float* __restrict__ hA,
                                                 const float* __restrict__ hB,
                                                 const float* __restrict__ hskip,
                                                 const int* __restrict__ row_ptr,
                                                 const int* __restrict__ csr_src,
                                                 const float* __restrict__ postW,
                                                 const float* __restrict__ postb,
                                                 const float* __restrict__ linW,
                                                 const float* __restrict__ linb,
                                                 const float* __restrict__ scalars,
                                                 float* __restrict__ out) {
  __shared__ float smem[2 * 13 * 4 * 64];   // 26624 B
  int w = threadIdx.x >> 6, lane = threadIdx.x & 63;
  int n = blockIdx.x * 4 + w;               // N divisible by 4
  int t = lane >> 5, fb = (lane & 31) * 2;
  int off = t * 64 + fb;

  // ---- phase A: aggregation, 4 loads in flight
  float2 a = *(const float2*)&hA[(size_t)n * 128 + off];
  int rp0 = __builtin_amdgcn_readfirstlane(row_ptr[n]);
  int rp1 = __builtin_amdgcn_readfirstlane(row_ptr[n + 1]);
  float sx0=0,sy0=0,qx0=0,qy0=0, sx1=0,sy1=0,qx1=0,qy1=0;
  float mnx0=INFINITY,mny0=INFINITY,mxx0=-INFINITY,mxy0=-INFINITY;
  float mnx1=INFINITY,mny1=INFINITY,mxx1=-INFINITY,mxy1=-INFINITY;
  int i = rp0;
  int end4 = rp0 + ((rp1 - rp0) & ~3);
  if (i < end4) {
    int s0 = csr_src[i], s1 = csr_src[i+1], s2 = csr_src[i+2], s3 = csr_src[i+3];
    while (true) {
      float2 v0 = *(const float2*)&hB[(size_t)s0 * 128 + off];
      float2 v1 = *(const float2*)&hB[(size_t)s1 * 128 + off];
      float2 v2 = *(const float2*)&hB[(size_t)s2 * 128 + off];
      float2 v3 = *(const float2*)&hB[(size_t)s3 * 128 + off];
      i += 4;
      bool more = (i < end4);
      if (more) { s0 = csr_src[i]; s1 = csr_src[i+1]; s2 = csr_src[i+2]; s3 = csr_src[i+3]; }
      float e0x = v0.x + a.x, e0y = v0.y + a.y;
      float e1x = v1.x + a.x, e1y = v1.y + a.y;
      float e2x = v2.x + a.x, e2y = v2.y + a.y;
      float e3x = v3.x + a.x, e3y = v3.y + a.y;
      sx0 += e0x; qx0 = fmaf(e0x,e0x,qx0); mnx0 = fminf(mnx0,e0x); mxx0 = fmaxf(mxx0,e0x);
      sy0 += e0y; qy0 = fmaf(e0y,e0y,qy0); mny0 = fminf(mny0,e0y); mxy0 = fmaxf(mxy0,e0y);
      sx1 += e1x; qx1 = fmaf(e1x,e1x,qx1); mnx1 = fminf(mnx1,e1x); mxx1 = fmaxf(mxx1,e1x);
      sy1 += e1y; qy1 = fmaf(e1y,e1y,qy1); mny1 = fminf(mny1,e1y); mxy1 = fmaxf(mxy1,e1y);
      sx0 += e2x; qx0 = fmaf(e2x,e2x,qx0); mnx0 = fminf(mnx0,e2x); mxx0 = fmaxf(mxx0,e2x);
      sy0 += e2y; qy0 = fmaf(e2y,e2y,qy0); mny0 = fminf(mny0,e2y); mxy0 = fmaxf(mxy0,e2y);
      sx1 += e3x; qx1 = fmaf(e3x,e3x,qx1); mnx1 = fminf(mnx1,e3x); mxx1 = fmaxf(mxx1,e3x);
      sy1 += e3y; qy1 = fmaf(e3y,e3y,qy1); mny1 = fminf(mny1,e3y); mxy1 = fmaxf(mxy1,e3y);
      if (!more) break;
    }
  }
  {   // masked tail: 0..3 edges, all loads issued together
    int r = rp1 - i;
    if (r > 0) {
      int e1i = (r > 1) ? i + 1 : i;
      int e2i = (r > 2) ? i + 2 : i;
      int t0 = csr_src[i], t1 = csr_src[e1i], t2 = csr_src[e2i];
      float2 u0 = *(const float2*)&hB[(size_t)t0 * 128 + off];
      float2 u1 = *(const float2*)&hB[(size_t)t1 * 128 + off];
      float2 u2 = *(const float2*)&hB[(size_t)t2 * 128 + off];
      float ex = u0.x + a.x, ey = u0.y + a.y;
      sx0 += ex; qx0 = fmaf(ex,ex,qx0); mnx0 = fminf(mnx0,ex); mxx0 = fmaxf(mxx0,ex);
      sy0 += ey; qy0 = fmaf(ey,ey,qy0); mny0 = fminf(mny0,ey); mxy0 = fmaxf(mxy0,ey);
      if (r > 1) {
        ex = u1.x + a.x; ey = u1.y + a.y;
        sx1 += ex; qx1 = fmaf(ex,ex,qx1); mnx1 = fminf(mnx1,ex); mxx1 = fmaxf(mxx1,ex);
        sy1 += ey; qy1 = fmaf(ey,ey,qy1); mny1 = fminf(mny1,ey); mxy1 = fmaxf(mxy1,ey);
      }
      if (r > 2) {
        ex = u2.x + a.x; ey = u2.y + a.y;
        sx0 += ex; qx0 = fmaf(ex,ex,qx0); mnx0 = fminf(mnx0,ex); mxx0 = fmaxf(mxx0,ex);
        sy0 += ey; qy0 = fmaf(ey,ey,qy0); mny0 = fminf(mny0,ey); mxy0 = fmaxf(mxy0,ey);
      }
    }
  }
  int dg = rp1 - rp0;
  float cnt = (float)(dg > 0 ? dg : 1);
  float inv = 1.0f / cnt;
  float meanx = (sx0 + sx1) * inv, meany = (sy0 + sy1) * inv;
  float qx = qx0 + qx1, qy = qy0 + qy1;
  float sdx = sqrtf(fmaxf(qx * inv - meanx * meanx, 0.f) + STD_EPS);
  float sdy = sqrtf(fmaxf(qy * inv - meany * meany, 0.f) + STD_EPS);
  float mnx = fminf(mnx0, mnx1), mny = fminf(mny0, mny1);
  float mxx = fmaxf(mxx0, mxx1), mxy = fmaxf(mxy0, mxy1);
  if (dg == 0) { mnx = 0; mny = 0; mxx = 0; mxy = 0; }
  float avg = scalars[1];
  float ldv = logf(cnt + 1.f);
  float sA = ldv / avg, sB = avg / ldv;
  float2 hsv = *(const float2*)&hskip[(size_t)n * 64 + fb];

  // ---- phase B: 13 float2 writes, node-major layout (conflict-free)
  {
    float* bp = &smem[t * (13 * 256) + w * 64 + fb];
    *(float2*)&bp[0]        = make_float2(hsv.x, hsv.y);
    *(float2*)&bp[256]      = make_float2(meanx, meany);
    *(float2*)&bp[2 * 256]  = make_float2(mnx, mny);
    *(float2*)&bp[3 * 256]  = make_float2(mxx, mxy);
    *(float2*)&bp[4 * 256]  = make_float2(sdx, sdy);
    *(float2*)&bp[5 * 256]  = make_float2(meanx * sA, meany * sA);
    *(float2*)&bp[6 * 256]  = make_float2(mnx * sA, mny * sA);
    *(float2*)&bp[7 * 256]  = make_float2(mxx * sA, mxy * sA);
    *(float2*)&bp[8 * 256]  = make_float2(sdx * sA, sdy * sA);
    *(float2*)&bp[9 * 256]  = make_float2(meanx * sB, meany * sB);
    *(float2*)&bp[10 * 256] = make_float2(mnx * sB, mny * sB);
    *(float2*)&bp[11 * 256] = make_float2(mxx * sB, mxy * sB);
    *(float2*)&bp[12 * 256] = make_float2(sdx * sB, sdy * sB);
  }
  __syncthreads();

  // ---- phase C: post matmul; wave w covers hf-quarter [w*16, w*16+16)
  float c0 = 0, c1 = 0, c2 = 0, c3 = 0;
  {
    int tC = lane >> 5, g = lane & 31, hf0 = w * 16;
    const float* pwt = &postW[(size_t)tC * (832 * 32) + g];
#pragma unroll
    for (int feat = 0; feat < 13; feat++) {
      const float* lp = &smem[(tC * 13 + feat) * 256 + hf0];
      const float* pw = pwt + (size_t)(feat * 64 + hf0) * 32;
#pragma unroll
      for (int j = 0; j < 16; j += 4) {
        float w0 = pw[j * 32], w1 = pw[j * 32 + 32], w2 = pw[j * 32 + 64], w3 = pw[j * 32 + 96];
        float4 v0 = *(const float4*)(lp + j);
        float4 v1 = *(const float4*)(lp + 64 + j);
        float4 v2 = *(const float4*)(lp + 128 + j);
        float4 v3 = *(const float4*)(lp + 192 + j);
        c0 = fmaf(v0.w, w3, fmaf(v0.z, w2, fmaf(v0.y, w1, fmaf(v0.x, w0, c0))));
        c1 = fmaf(v1.w, w3, fmaf(v1.z, w2, fmaf(v1.y, w1, fmaf(v1.x, w0, c1))));
        c2 = fmaf(v2.w, w3, fmaf(v2.z, w2, fmaf(v2.y, w1, fmaf(v2.x, w0, c2))));
        c3 = fmaf(v3.w, w3, fmaf(v3.z, w2, fmaf(v3.y, w1, fmaf(v3.x, w0, c3))));
      }
    }
  }
  __syncthreads();   // all smem reads done -> safe to alias

  // ---- partials into aliased region, rep-swizzled (2-way max)
  {
    int sw = (w + (lane >> 3)) & 3;
    smem[((0 * 64 + lane) << 2) + sw] = c0;
    smem[((1 * 64 + lane) << 2) + sw] = c1;
    smem[((2 * 64 + lane) << 2) + sw] = c2;
    smem[((3 * 64 + lane) << 2) + sw] = c3;
  }
  __syncthreads();

  // ---- phase D: reduce (order-agnostic sum of 4 components) + postb
  {
    float4 p = *(const float4*)&smem[(w * 64 + lane) << 2];
    float po = p.x + p.y + p.z + p.w + postb[lane];
    smem[1024 + w * 64 + lane] = po;
  }
  __syncthreads();

  // ---- lin epilogue
  {
    float acc = linb[lane];
    const float* lw = linW + lane;
    const float* pov = &smem[1024 + w * 64];
#pragma unroll
    for (int i2 = 0; i2 < 64; i2 += 4) {
      float4 p = *(const float4*)&pov[i2];
      acc = fmaf(p.x, lw[i2 * 64], acc);
      acc = fmaf(p.y, lw[(i2 + 1) * 64], acc);
      acc = fmaf(p.z, lw[(i2 + 2) * 64], acc);
      acc = fmaf(p.w, lw[(i2 + 3) * 64], acc);
    }
    out[(size_t)n * 64 + lane] = acc;
  }
}

// ------------------------------------------------------------------ BN stats
__global__ __launch_bounds__(256) void k_bnstats(const float* __restrict__ y,
                                                 float* __restrict__ bnsum,
                                                 float* __restrict__ bnsumsq) {
  __shared__ float r1[256], r2[256];
  int c = threadIdx.x & 63, r = threadIdx.x >> 6;
  float s = 0, q = 0;
  for (int n = blockIdx.x * 4 + r; n < N_NODES; n += gridDim.x * 4) {
    float v = y[(size_t)n * 64 + c];
    s += v; q = fmaf(v, v, q);
  }
  r1[threadIdx.x] = s; r2[threadIdx.x] = q; __syncthreads();
  if (threadIdx.x < 64) {
    s = r1[threadIdx.x] + r1[threadIdx.x + 64] + r1[threadIdx.x + 128] + r1[threadIdx.x + 192];
    q = r2[threadIdx.x] + r2[threadIdx.x + 64] + r2[threadIdx.x + 128] + r2[threadIdx.x + 192];
    atomicAdd(&bnsum[threadIdx.x], s);
    atomicAdd(&bnsumsq[threadIdx.x], q);
  }
}

__global__ void k_bnfin(const float* __restrict__ bnsum, const float* __restrict__ bnsumsq,
                        const float* __restrict__ gamma, const float* __restrict__ beta,
                        float* __restrict__ bnscale, float* __restrict__ bnshift) {
  int c = threadIdx.x;
  if (c < 64) {
    float mu = bnsum[c] * (1.f / N_NODES);
    float var = bnsumsq[c] * (1.f / N_NODES) - mu * mu;
    float sc = gamma[c] / sqrtf(var + BN_EPS);
    bnscale[c] = sc;
    bnshift[c] = fmaf(-mu, sc, beta[c]);
  }
}

// ================================================================== launcher
extern "C" void kernel_launch(void* const* d_in, const int* in_sizes, int n_in,
                              void* d_out, int out_size, void* d_ws, size_t ws_size,
                              hipStream_t stream) {
  const float* x      = (const float*)d_in[0];
  const float* embW   = (const float*)d_in[1];
  const float* embB   = (const float*)d_in[2];
  const float* preW1  = (const float*)d_in[3];
  const float* preb1  = (const float*)d_in[4];
  const float* postW1 = (const float*)d_in[5];
  const float* postb1 = (const float*)d_in[6];
  const float* linW1  = (const float*)d_in[7];
  const float* linb1  = (const float*)d_in[8];
  const float* gamma  = (const float*)d_in[9];
  const float* beta   = (const float*)d_in[10];
  const float* preW2  = (const float*)d_in[11];
  const float* preb2  = (const float*)d_in[12];
  const float* postW2 = (const float*)d_in[13];
  const float* postb2 = (const float*)d_in[14];
  const float* linW2  = (const float*)d_in[15];
  const float* linb2  = (const float*)d_in[16];
  const int*   src    = (const int*)d_in[17];
  const int*   dst    = (const int*)d_in[18];
  float* out = (float*)d_out;

  char* w = (char*)d_ws;
  size_t o = 0;
  int*   deg     = (int*)(w + o);   o += (size_t)N_NODES * 4;
  float* scalars = (float*)(w + o); o += 64;
  float* bnsum   = (float*)(w + o); o += 256;
  float* bnsumsq = (float*)(w + o); o += 256;
  float* bnscale = (float*)(w + o); o += 256;
  float* bnshift = (float*)(w + o); o += 256;
  size_t zero_len = o;
  o = (o + 255) & ~(size_t)255;
  int* partials = (int*)(w + o);  o += 256;
  int* row_ptr  = (int*)(w + o);  o += (size_t)(N_NODES + 1) * 4; o = (o + 255) & ~(size_t)255;
  int* cursor   = (int*)(w + o);  o += (size_t)N_NODES * 4;       o = (o + 255) & ~(size_t)255;
  int* csr      = (int*)(w + o);  o += (size_t)E_EDGES * 4;       o = (o + 255) & ~(size_t)255;
  float* h1 = (float*)(w + o); o += (size_t)N_NODES * 64 * 4;
  float* y1 = (float*)(w + o); o += (size_t)N_NODES * 64 * 4;
  float* h2 = (float*)(w + o); o += (size_t)N_NODES * 64 * 4;
  float* hA = (float*)(w + o); o += (size_t)N_NODES * 128 * 4;
  float* hB = (float*)(w + o); o += (size_t)N_NODES * 128 * 4;

  hipMemsetAsync(w, 0, zero_len, stream);

  const int NBLK_SCAN = (N_NODES + 1023) / 1024;   // 49
  k_hist<<<(E_EDGES + 255) / 256, 256, 0, stream>>>(dst, deg);
  k_sumlog<<<(N_NODES + 255) / 256, 256, 0, stream>>>(deg, scalars);
  k_scan_part<<<NBLK_SCAN, 256, 0, stream>>>(deg, partials);
  k_scan_mid<<<1, 64, 0, stream>>>(partials, NBLK_SCAN, scalars);
  k_scan_final<<<NBLK_SCAN, 256, 0, stream>>>(deg, partials, row_ptr, cursor);
  k_scatter<<<(E_EDGES + 255) / 256, 256, 0, stream>>>(src, dst, cursor, csr);

  k_embed<<<768, 256, 0, stream>>>(x, embW, embB, h1);

  // ----- layer 1
  k_preab<false><<<1024, 256, 0, stream>>>(h1, preW1, preb1, nullptr, nullptr, nullptr, hA, hB);
  k_conv<<<N_NODES / 4, 256, 0, stream>>>(hA, hB, h1, row_ptr, csr,
                                          postW1, postb1, linW1, linb1, scalars, y1);
  // ----- batchnorm
  k_bnstats<<<256, 256, 0, stream>>>(y1, bnsum, bnsumsq);
  k_bnfin<<<1, 64, 0, stream>>>(bnsum, bnsumsq, gamma, beta, bnscale, bnshift);

  // ----- layer 2 (BN+relu fused into staging; h2 materialized for skip)
  k_preab<true><<<1024, 256, 0, stream>>>(y1, preW2, preb2, bnscale, bnshift, h2, hA, hB);
  k_conv<<<N_NODES / 4, 256, 0, stream>>>(hA, hB, h2, row_ptr, csr,
                                          postW2, postb2, linW2, linb2, scalars, out);
}